// Round 6
// baseline (190.422 us; speedup 1.0000x reference)
//
#include <hip/hip_runtime.h>

// NIGnet: X -> 64x [Y = X@W.T + b; X = (tanh(Y)+Y)/2] -> X@fW.T -> L2 normalize.
// Calibration (R1-R5): full-rate fp32 = 2 cyc/wave64; trans (v_exp/v_rcp) issue
// ~9.3 cyc/wave64 (fit from VALUBusy=0.82 @ 119.5us); packed fp32 adds nothing
// (157.3 TF peak == unpacked rate). Op mix 5 full + 2 trans per value is optimal:
// batched-rcp ~ +2%, poly-in-q and pure-poly tanh are net losers at T=9.3.
// Remaining margin = ~18% no-issue stall. R6 attacks it:
//  - KPT=16: 16 independent exp->rcp chains per wave (state forces allocator wide;
//    __launch_bounds__(256,4) = 128-VGPR budget; 1024 blocks = 4 waves/SIMD, same
//    total issue).
//  - depth-2 W/b prefetch ring: ~920 cyc slack per s_load instead of ~460.

#define KPT 16         // points per thread (8 float4 chunks)
#define BLOCK 256

__global__ __launch_bounds__(BLOCK, 4) void nig_kernel(
    const float* __restrict__ X_in,
    const float* __restrict__ Ws,    // [L,2,2] row-major
    const float* __restrict__ bs,    // [L,2]
    const float* __restrict__ fW,    // [2,2]
    float* __restrict__ out,
    int M,                           // float4 chunks = N/2
    int L)
{
    const int tid = blockIdx.x * blockDim.x + threadIdx.x;
    const int nthreads = gridDim.x * blockDim.x;
    const float4* __restrict__ in4 = (const float4*)X_in;
    float4* __restrict__ out4 = (float4*)out;

    const float C     = 2.8853900817779268f;   // 2*log2(e)
    const float halfC = 1.4426950408889634f;   // C/2

    // State scaled by C: u = C*x. exp2(y_u) = exp(2*y). Final normalize
    // cancels the uniform scale, so no un-scale needed.
    float u0[KPT], u1[KPT];
    int idx[KPT / 2]; bool ok[KPT / 2];
    #pragma unroll
    for (int j = 0; j < KPT / 2; ++j) {
        idx[j] = tid + j * nthreads;
        ok[j] = idx[j] < M;
        float4 v = ok[j] ? in4[idx[j]] : make_float4(0.f, 0.f, 0.f, 0.f);
        u0[2 * j]     = v.x * C; u1[2 * j]     = v.y * C;
        u0[2 * j + 1] = v.z * C; u1[2 * j + 1] = v.w * C;
    }

    const float4* Ws4 = (const float4*)Ws;
    const float2* bs2 = (const float2*)bs;

    // Depth-2 prefetch ring (L is even: 64 layers).
    float4 wA = Ws4[0]; float2 bA = bs2[0];
    float4 wB = Ws4[1]; float2 bB = bs2[1];

    for (int l = 0; l < L; l += 2) {
        const int lp2 = (l + 2 < L) ? (l + 2) : (L - 1);
        const int lp3 = (l + 3 < L) ? (l + 3) : (L - 1);
        float4 wnA = Ws4[lp2]; float2 bnA = bs2[lp2];   // s_load, used 2 layers out
        float4 wnB = Ws4[lp3]; float2 bnB = bs2[lp3];

        {   // layer l  (weights wA/bA)
            const float cb0 = C * bA.x, cb1 = C * bA.y;
            #pragma unroll
            for (int k = 0; k < KPT; ++k) {
                float y0 = fmaf(wA.x, u0[k], fmaf(wA.y, u1[k], cb0));
                float y1 = fmaf(wA.z, u0[k], fmaf(wA.w, u1[k], cb1));
                float e0 = __builtin_amdgcn_exp2f(y0);
                float e1 = __builtin_amdgcn_exp2f(y1);
                float r0 = __builtin_amdgcn_rcpf(e0 + 1.0f);
                float r1 = __builtin_amdgcn_rcpf(e1 + 1.0f);
                u0[k] = fmaf(-C, r0, fmaf(0.5f, y0, halfC));
                u1[k] = fmaf(-C, r1, fmaf(0.5f, y1, halfC));
            }
        }
        {   // layer l+1  (weights wB/bB)
            const float cb0 = C * bB.x, cb1 = C * bB.y;
            #pragma unroll
            for (int k = 0; k < KPT; ++k) {
                float y0 = fmaf(wB.x, u0[k], fmaf(wB.y, u1[k], cb0));
                float y1 = fmaf(wB.z, u0[k], fmaf(wB.w, u1[k], cb1));
                float e0 = __builtin_amdgcn_exp2f(y0);
                float e1 = __builtin_amdgcn_exp2f(y1);
                float r0 = __builtin_amdgcn_rcpf(e0 + 1.0f);
                float r1 = __builtin_amdgcn_rcpf(e1 + 1.0f);
                u0[k] = fmaf(-C, r0, fmaf(0.5f, y0, halfC));
                u1[k] = fmaf(-C, r1, fmaf(0.5f, y1, halfC));
            }
        }
        wA = wnA; bA = bnA; wB = wnB; bB = bnB;
    }

    // Final linear + L2 normalize (uniform scale C cancels).
    const float g0 = fW[0], g1 = fW[1], g2 = fW[2], g3 = fW[3];

    #pragma unroll
    for (int j = 0; j < KPT / 2; ++j) {
        if (!ok[j]) continue;
        float4 o;
        #pragma unroll
        for (int h = 0; h < 2; ++h) {
            const int k = 2 * j + h;
            float z0 = fmaf(g0, u0[k], g1 * u1[k]);
            float z1 = fmaf(g2, u0[k], g3 * u1[k]);
            float s  = fmaf(z0, z0, z1 * z1);
            float n  = __builtin_amdgcn_sqrtf(s);
            float iv = __builtin_amdgcn_rcpf(fmaxf(n, 1e-12f));
            if (h == 0) { o.x = z0 * iv; o.y = z1 * iv; }
            else        { o.z = z0 * iv; o.w = z1 * iv; }
        }
        out4[idx[j]] = o;
    }
}

extern "C" void kernel_launch(void* const* d_in, const int* in_sizes, int n_in,
                              void* d_out, int out_size, void* d_ws, size_t ws_size,
                              hipStream_t stream) {
    // 0=T(unused), 1=closed_manifold [N,2], 2=Ws [L,2,2], 3=bs [L,2], 4=final_W [2,2]
    const float* X  = (const float*)d_in[1];
    const float* Ws = (const float*)d_in[2];
    const float* bs = (const float*)d_in[3];
    const float* fW = (const float*)d_in[4];
    float* out = (float*)d_out;

    const int L = in_sizes[2] / 4;
    const int M = in_sizes[1] / 4;
    const int threads = (M + (KPT / 2) - 1) / (KPT / 2);
    const int grid = (threads + BLOCK - 1) / BLOCK;

    nig_kernel<<<grid, BLOCK, 0, stream>>>(X, Ws, bs, fW, out, M, L);
}